// Round 9
// baseline (176.570 us; speedup 1.0000x reference)
//
#include <hip/hip_runtime.h>

#define N_B   64
#define T_S   32
#define DIM   12288          // 3*64*64
#define ROWS  2048           // N_B*T_S
#define NCOL  12             // used GEMM columns (3 obj * 4)
#define RPBK  64             // rows per block
#define KB    128            // k-range per block
#define KSPL  (DIM / KB)     // 96 k-segments
#define XSTR  133            // padded LDS row stride (133%32=5 -> 2-way only)

typedef float f4 __attribute__((ext_vector_type(4)));

// ---------------- Kernel 1: transpose-through-LDS skinny GEMM --------------
// Grid: 32 row-groups x 96 k-segments = 3072 blocks, 256 threads.
// Phase A: stage x tile (64 rows x 128 k) into LDS, fully coalesced.
// Phase B: lane = row; each lane accumulates acc[12] privately from its own
//          row (LDS, 2-way bank = free). W is wave-uniform -> s_load (scalar
//          pipe). ZERO cross-lane shuffles -> LDS pipe nearly idle.
// Phase C: 4 waves (same rows, different k-quarter) sum via small LDS pack.
__global__ __launch_bounds__(256) void k_gemm(const float* __restrict__ x,
                                              const float* __restrict__ W,
                                              float* __restrict__ part) {
    __shared__ float xs[RPBK * XSTR];     // 34 KB; reused for the pack
    const int bx  = blockIdx.x;
    const int rg  = bx / KSPL;            // row group 0..31
    const int sg  = bx - rg * KSPL;       // k segment 0..95
    const int tid = threadIdx.x;
    const int r0  = rg * RPBK;
    const int kb0 = sg * KB;

    // ---- Phase A: coalesced stage (each 32-thread group = 512B of one row)
#pragma unroll
    for (int it = 0; it < 8; ++it) {
        const int flat = tid + it * 256;            // 0..2047
        const int row  = flat >> 5;
        const int c4   = flat & 31;
        const f4 v = *(const f4*)(x + (size_t)(r0 + row) * DIM + kb0 + c4 * 4);
        *(f4*)(xs + row * XSTR + c4 * 4) = v;
    }
    __syncthreads();

    // ---- Phase B: lane = row, wave w covers k-quarter [w*32, w*32+32)
    const int w    = __builtin_amdgcn_readfirstlane(tid >> 6);  // scalar
    const int lane = tid & 63;

    f4 xr[8];
#pragma unroll
    for (int i = 0; i < 8; ++i)
        xr[i] = *(const f4*)(xs + lane * XSTR + w * 32 + i * 4);

    float acc[NCOL];
#pragma unroll
    for (int c = 0; c < NCOL; ++c) acc[c] = 0.f;

    const float* wbase = W + (size_t)(kb0 + w * 32) * 24;  // scalar base
#pragma unroll
    for (int i = 0; i < 8; ++i) {
#pragma unroll
        for (int kk = 0; kk < 4; ++kk) {
            const float  xv = xr[i][kk];
            const float* wr = wbase + (i * 4 + kk) * 24;   // uniform -> s_load
            acc[0]  += xv * wr[0];  acc[1]  += xv * wr[1];
            acc[2]  += xv * wr[2];  acc[3]  += xv * wr[3];
            acc[4]  += xv * wr[8];  acc[5]  += xv * wr[9];
            acc[6]  += xv * wr[10]; acc[7]  += xv * wr[11];
            acc[8]  += xv * wr[16]; acc[9]  += xv * wr[17];
            acc[10] += xv * wr[18]; acc[11] += xv * wr[19];
        }
    }
    __syncthreads();   // xs reads done -> safe to reuse as pack

    // ---- Phase C: pack[w][row][c] (stride 13 -> odd, 2-way only)
#pragma unroll
    for (int c = 0; c < NCOL; ++c)
        xs[w * (64 * 13) + lane * 13 + c] = acc[c];
    __syncthreads();

    // sum the 4 wave-partials, store 768 floats coalesced
#pragma unroll
    for (int j = 0; j < 3; ++j) {
        const int i   = tid + j * 256;     // 0..767 = row*12+c
        const int row = i / NCOL;
        const int c   = i - row * NCOL;
        float s = 0.f;
#pragma unroll
        for (int ww = 0; ww < 4; ++ww)
            s += xs[ww * (64 * 13) + row * 13 + c];
        part[(size_t)sg * (ROWS * NCOL) + (size_t)rg * (RPBK * NCOL) + i] = s;
    }
}

// ---------------- Kernel 2: reduce split-K + bias + sigmoid constrain ------
__global__ __launch_bounds__(256) void k_reduce(const float* __restrict__ part,
                                                const float* __restrict__ b_enc,
                                                float* __restrict__ zbuf) {
    const int rc = blockIdx.x * 256 + threadIdx.x;    // 0..24575 = row*12+c
    float s = 0.f;
#pragma unroll 8
    for (int i = 0; i < KSPL; ++i) s += part[(size_t)i * (ROWS * NCOL) + rc];

    const int row = rc / NCOL;
    const int c   = rc - row * NCOL;
    const int o   = c >> 2;
    const int cp  = c & 3;
    s += b_enc[o * 8 + cp];
    const float sg = 1.f / (1.f + expf(-s));
    float v;
    if (cp == 0)      v = sg * 0.7f + 0.1f;
    else if (cp == 1) v = sg * 0.5f + 0.75f;
    else              v = (2.f * sg - 1.f) * 0.9f;
    zbuf[rc] = v;
}

// ---------------- Kernel 3: match + fix_supair + output --------------------
__global__ __launch_bounds__(64) void k_post(const float* __restrict__ zbuf,
                                             float* __restrict__ out) {
    __shared__ float z[T_S * NCOL];
    __shared__ float zm[T_S * NCOL];
    __shared__ float zf[T_S * NCOL];
    __shared__ int   perm[T_S];
    const int b   = blockIdx.x;
    const int tid = threadIdx.x;

#pragma unroll
    for (int i = 0; i < 6; ++i)
        z[tid + 64 * i] = zbuf[b * 384 + tid + 64 * i];
    __syncthreads();

    if (tid == 0) {
        float px0 = z[2],  py0 = z[3];
        float px1 = z[6],  py1 = z[7];
        float px2 = z[10], py2 = z[11];
        for (int t = 1; t < T_S; ++t) {
            const int base = t * 12;
            const float cx0 = z[base + 2],  cy0 = z[base + 3];
            const float cx1 = z[base + 6],  cy1 = z[base + 7];
            const float cx2 = z[base + 10], cy2 = z[base + 11];

            float dx, dy;
            dx = px0 - cx0; dy = py0 - cy0; const float e00 = dx * dx + dy * dy;
            dx = px0 - cx1; dy = py0 - cy1; const float e01 = dx * dx + dy * dy;
            dx = px0 - cx2; dy = py0 - cy2; const float e02 = dx * dx + dy * dy;
            dx = px1 - cx0; dy = py1 - cy0; const float e10 = dx * dx + dy * dy;
            dx = px1 - cx1; dy = py1 - cy1; const float e11 = dx * dx + dy * dy;
            dx = px1 - cx2; dy = py1 - cy2; const float e12 = dx * dx + dy * dy;
            dx = px2 - cx0; dy = py2 - cy0; const float e20 = dx * dx + dy * dy;
            dx = px2 - cx1; dy = py2 - cy1; const float e21 = dx * dx + dy * dy;
            dx = px2 - cx2; dy = py2 - cy2; const float e22 = dx * dx + dy * dy;

            auto amin3 = [](float a0, float a1, float a2) {
                int j = 0; float e = a0;
                if (a1 < e) { e = a1; j = 1; }
                if (a2 < e) { j = 2; }
                return j;
            };
            int i0 = amin3(e00, e01, e02);
            int i1 = amin3(e10, e11, e12);
            int i2 = amin3(e20, e21, e22);
            const bool ok = (i1 != i0) && (i2 != i1) && (i0 != i2);
            if (!ok) {
                float u0 = 0.f, u1 = 0.f, u2 = 0.f;
                i0 = amin3(e00, e01, e02);
                if (i0 == 0) u0 = 1.f; else if (i0 == 1) u1 = 1.f; else u2 = 1.f;
                i1 = amin3(e10 + u0 * 1e12f, e11 + u1 * 1e12f, e12 + u2 * 1e12f);
                if (i1 == 0) u0 = 1.f; else if (i1 == 1) u1 = 1.f; else u2 = 1.f;
                i2 = amin3(e20 + u0 * 1e12f, e21 + u1 * 1e12f, e22 + u2 * 1e12f);
            }
            perm[t] = i0 * 9 + i1 * 3 + i2;
            px0 = (i0 == 0) ? cx0 : (i0 == 1) ? cx1 : cx2;
            py0 = (i0 == 0) ? cy0 : (i0 == 1) ? cy1 : cy2;
            px1 = (i1 == 0) ? cx0 : (i1 == 1) ? cx1 : cx2;
            py1 = (i1 == 0) ? cy0 : (i1 == 1) ? cy1 : cy2;
            px2 = (i2 == 0) ? cx0 : (i2 == 1) ? cx1 : cx2;
            py2 = (i2 == 0) ? cy0 : (i2 == 1) ? cy1 : cy2;
        }
    }
    __syncthreads();

#pragma unroll
    for (int ii = 0; ii < 6; ++ii) {
        const int i  = tid + 64 * ii;
        const int t  = i / 12;
        const int j  = i - t * 12;
        const int k  = j >> 2;
        const int ch = j & 3;
        int p = k;
        if (t > 0) {
            const int code = perm[t];
            p = (k == 0) ? code / 9 : (k == 1) ? (code % 9) / 3 : code % 3;
        }
        zm[i] = z[t * 12 + p * 4 + ch];
    }
    __syncthreads();

#pragma unroll
    for (int ii = 0; ii < 6; ++ii) {
        const int i  = tid + 64 * ii;
        const int t  = i / 12;
        const int j  = i - t * 12;
        const int o  = j >> 2;
        const int cc = j & 1;
        const int mb = o * 4 + cc;
        const float pd = (t >= 1)  ? fabsf(zm[t * 12 + mb] - zm[(t - 1) * 12 + mb]) : 0.f;
        const float ad = (t <= 30) ? fabsf(zm[(t + 1) * 12 + mb] - zm[t * 12 + mb]) : 0.f;
        const bool  m  = (pd > 0.095f) && (ad > 0.095f);
        const float sm = (t >= 1 && t <= 30)
                             ? (zm[(t - 1) * 12 + j] + zm[(t + 1) * 12 + j]) * 0.5f
                             : 0.f;
        zf[i] = m ? sm : zm[t * 12 + j];
    }
    __syncthreads();

    for (int i = tid; i < 31 * 12; i += 64) {
        const int t  = i / 12;
        const int j  = i - t * 12;
        const int o  = j >> 2;
        const int c2 = j & 3;
        const int pb = o * 4 + 2 + (c2 & 1);
        float v;
        if (c2 < 2) v = zf[(t + 1) * 12 + pb] + 1.f;
        else        v = (zf[(t + 1) * 12 + pb] - zf[t * 12 + pb]) * 10.f;
        out[b * 372 + i] = v;
    }
}

extern "C" void kernel_launch(void* const* d_in, const int* in_sizes, int n_in,
                              void* d_out, int out_size, void* d_ws, size_t ws_size,
                              hipStream_t stream) {
    (void)in_sizes; (void)n_in; (void)out_size; (void)ws_size;
    const float* x     = (const float*)d_in[0];
    const float* W_enc = (const float*)d_in[1];
    const float* b_enc = (const float*)d_in[2];
    float* out  = (float*)d_out;

    float* zbuf = (float*)d_ws;                     // 24576 floats
    float* part = zbuf + ROWS * NCOL;               // 96*24576 floats (~9.4 MB)

    k_gemm  <<<(ROWS / RPBK) * KSPL, 256, 0, stream>>>(x, W_enc, part);
    k_reduce<<<(ROWS * NCOL) / 256, 256, 0, stream>>>(part, b_enc, zbuf);
    k_post  <<<N_B, 64, 0, stream>>>(zbuf, out);
}